// Round 9
// baseline (227.172 us; speedup 1.0000x reference)
//
#include <hip/hip_runtime.h>
#include <stdint.h>

// B=8,H=16,S=1024,D=64 causal+length-masked attention. fp32 in/out.
// R15: occupancy doubling. Six schedules (R7-R14) all land 53-58us with
// ~9.7 waves/CU (30%): per-CU pipe busy LDS~26us > VALU~18 > MFMA~9, wall
// 53 -> ~40% no-issue gap = per-block phase latency, uncovered at 4
// blocks/CU (grid- and LDS-limited). Fix the MACRO numbers:
//  - 64-row blocks, grid 2048 = 8 blocks/CU ALL resident at t=0 (zero
//    dispatch tail); chunk order pair-interleaved {0,15,1,14,..} so each
//    CU's 8-block set has ~equal tile sum.
//  - single-buffered LDS (K 8KB + V 8KB = 16KB) with 2 barriers/phase:
//    {bar -> compute -> bar -> restage}. Exposed restage latency is block
//    LATENCY, covered by 8-way block concurrency (the double-buffer only
//    mattered when 2-4 blocks were resident).
//  - __launch_bounds__(256,8) pins VGPR<=64 (R14 body = 56) so 8 waves/SIMD
//    is real. Spill tripwire: WRITE_SIZE must stay ~33MB.
// Keeps: R14 batched body (kb[4]/vb[4] halves, one 16-exp batch), deferred
// cross-quad rowsum, zero-shuffle PV (V key-permuted in prep), cvt_pk,
// XCD swizzle (16 bh = 4MB K/V per XCD L2), chunk-major workspace, prep.
#define B_ 8
#define H_ 16
#define S_ 1024
#define D_ 64
#define C1_ 0.18033688f          // 0.125 * log2(e)
#define C2_ 23.08312065f         // 16 * log2(e)
#define BHSD (B_ * H_ * S_ * D_)

typedef __attribute__((ext_vector_type(8))) short bf16x8;
typedef __attribute__((ext_vector_type(4))) float f32x4;
typedef __attribute__((ext_vector_type(4))) unsigned short us4;

__device__ __forceinline__ unsigned short f2bf(float f) {
  union { float f; uint32_t u; } v; v.f = f;
  return (unsigned short)((v.u + 0x7fffu + ((v.u >> 16) & 1u)) >> 16);  // RNE
}
__device__ __forceinline__ uint32_t cvtpk(float lo, float hi) {  // HW RNE pack
  uint32_t r;
  asm("v_cvt_pk_bf16_f32 %0, %1, %2" : "=v"(r) : "v"(lo), "v"(hi));
  return r;
}
__device__ __forceinline__ float fexp2(float x) {
#if __has_builtin(__builtin_amdgcn_exp2f)
  return __builtin_amdgcn_exp2f(x);
#else
  return exp2f(x);
#endif
}

// Chunk-major tile layout (per bh, per 64-key tile kt; 512 chunks of 8 bf16):
//   chunk c = ((nt*2+kc)*4+quad)*16 + l16
//   K  chunk holds K [key = kt*64 + nt*16 + l16][d = kc*32 + quad*8 + j]
//   Vt chunk holds Vt[d   = nt*16 + l16       ]
//                    [key = kt*64 + kc*32 + (j>>2)*16 + quad*4 + (j&3)]
// (V's j-mapping matches the QK C-layout so PV needs NO P redistribution.)
__global__ __launch_bounds__(256) void prep_kv_kernel(
    const float* __restrict__ kg, const float* __restrict__ vg,
    unsigned short* __restrict__ kws, unsigned short* __restrict__ vtws) {
  __shared__ unsigned short t[64 * 68];
  const int tid = threadIdx.x;
  const int kt  = blockIdx.x & 15;
  const int bh  = blockIdx.x >> 4;
  const size_t off  = ((size_t)bh * S_ + kt * 64) * D_;
  const size_t tout = (size_t)(bh * 16 + kt) * 4096;
  // K: coalesced float4 load -> LDS [key][d] -> d-contiguous chunk gather
#pragma unroll
  for (int i = 0; i < 4; i++) {
    int c = tid + 256 * i;                 // 1024 float4 = 64x64 fp32 tile
    float4 val = *(const float4*)(kg + off + c * 4);
    int key = c >> 4, d0 = (c & 15) * 4;
    us4 o; o[0] = f2bf(val.x); o[1] = f2bf(val.y); o[2] = f2bf(val.z); o[3] = f2bf(val.w);
    *(us4*)(&t[key * 68 + d0]) = o;
  }
  __syncthreads();
#pragma unroll
  for (int i = 0; i < 2; i++) {
    int c = tid + 256 * i;
    int nt = c >> 7, kc = (c >> 6) & 1, quad = (c >> 4) & 3, l16 = c & 15;
    int key = nt * 16 + l16, d0 = kc * 32 + quad * 8;
    bf16x8 o;
#pragma unroll
    for (int j = 0; j < 8; j++) o[j] = (short)t[key * 68 + d0 + j];
    *(bf16x8*)(kws + tout + (size_t)c * 8) = o;
  }
  __syncthreads();                         // t reused for V
  // V: coalesced load -> LDS -> transposed chunk-major gather (permuted keys)
#pragma unroll
  for (int i = 0; i < 4; i++) {
    int c = tid + 256 * i;
    float4 val = *(const float4*)(vg + off + c * 4);
    int key = c >> 4, d0 = (c & 15) * 4;
    us4 o; o[0] = f2bf(val.x); o[1] = f2bf(val.y); o[2] = f2bf(val.z); o[3] = f2bf(val.w);
    *(us4*)(&t[key * 68 + d0]) = o;
  }
  __syncthreads();
#pragma unroll
  for (int i = 0; i < 2; i++) {
    int c = tid + 256 * i;
    int nt = c >> 7, kc = (c >> 6) & 1, quad = (c >> 4) & 3, l16 = c & 15;
    int d = nt * 16 + l16, kb2 = kc * 32 + quad * 4;
    bf16x8 o;
#pragma unroll
    for (int j = 0; j < 8; j++) {
      int key = kb2 + ((j >> 2) << 4) + (j & 3);
      o[j] = (short)t[key * 68 + d];
    }
    *(bf16x8*)(vtws + tout + (size_t)c * 8) = o;
  }
}

// ---- flash attention: 256 thr = 4 waves x 16 q-rows; one 64-row chunk ----
__global__ __launch_bounds__(256, 8) void attn_flash_kernel(
    const float* __restrict__ qg,
    const unsigned short* __restrict__ kws,   // chunk-major bf16 K tiles
    const unsigned short* __restrict__ vtws,  // chunk-major bf16 Vt tiles
    const void* __restrict__ posmask,
    const void* __restrict__ srcmask,
    float* __restrict__ outg)
{
  __shared__ unsigned short lds_k[4096];     // 8KB: one 64-key K tile
  __shared__ unsigned short lds_v[4096];     // 8KB: one 64-key Vt tile

  const int tid  = threadIdx.x;
  const int wave = tid >> 6;                 // 0..3
  const int lane = tid & 63;
  const int quad = lane >> 4;
  const int l16  = lane & 15;

  // Block p -> XCD p&7, i = p>>3 in [0,256): bh = xcd*16 + (i>>4)
  // (16 bh per XCD -> 4MB K/V resident in its L2); chunk = pairseq[i&15] =
  // {0,15,1,14,2,13,3,12,...} so any aligned 8-window has ~equal tile sum.
  const int p     = blockIdx.x;
  const int xcd   = p & 7;
  const int i     = p >> 3;
  const int bh    = xcd * 16 + (i >> 4);
  const int jj    = i & 15;
  const int chunk = (jj & 1) ? (15 - (jj >> 1)) : (jj >> 1);
  const int b     = bh >> 4;

  // mask element-width probe from position_mask (elem0=0, elem1=1)
  const uint8_t* pmb = (const uint8_t*)posmask;
  const int mode = pmb[1] ? 0 : (pmb[2] ? 1 : (pmb[4] ? 2 : 3));

  // wave-local source-length reduction (no LDS, no barrier, no atomic)
  int lm = S_;
  for (int ii = lane; ii < S_; ii += 64) {
    const int idx = b * S_ + ii;
    bool masked;
    if (mode == 0)      masked = ((const uint8_t*) srcmask)[idx] != 0;
    else if (mode == 1) masked = ((const uint16_t*)srcmask)[idx] != 0;
    else                masked = ((const uint32_t*)srcmask)[idx] != 0;
    if (masked) lm = min(lm, ii);
  }
  lm = min(lm, __shfl_xor(lm, 1));
  lm = min(lm, __shfl_xor(lm, 2));
  lm = min(lm, __shfl_xor(lm, 4));
  lm = min(lm, __shfl_xor(lm, 8));
  lm = min(lm, __shfl_xor(lm, 16));
  lm = min(lm, __shfl_xor(lm, 32));
  const int len = lm;

  const unsigned short* kt0 = kws  + (size_t)bh * 16 * 4096;
  const unsigned short* vt0 = vtws + (size_t)bh * 16 * 4096;

  const int qw = chunk * 64 + wave * 16;     // this wave's 16 q rows

  // Q B-frags (S^T form): lane l16 = qrow-local, quad*8+j = d
  bf16x8 qfrag[2];
#pragma unroll
  for (int kc = 0; kc < 2; kc++) {
    const float* qp = qg + ((size_t)bh * S_ + qw + l16) * D_ + kc * 32 + quad * 8;
    float4 a = *(const float4*)qp;
    float4 cc = *(const float4*)(qp + 4);
    union { bf16x8 v; uint32_t u[4]; } u;
    u.u[0] = cvtpk(a.x, a.y);  u.u[1] = cvtpk(a.z, a.w);
    u.u[2] = cvtpk(cc.x, cc.y); u.u[3] = cvtpk(cc.z, cc.w);
    qfrag[kc] = u.v;
  }

  f32x4 ofrag[4];
#pragma unroll
  for (int nt = 0; nt < 4; nt++) ofrag[nt] = (f32x4){0.f, 0.f, 0.f, 0.f};
  float l_i = 0.f;                           // per-lane PARTIAL (own quad's keys)

  const int kend  = min(chunk * 64 + 64, len);
  const int ntile = (kend + 63) >> 6;        // block-uniform (chunk,len uniform)
  const int km    = min(qw + l16, len - 1);

  // prologue: stage tile 0 (global -> reg -> LDS; compiler inserts waitcnts)
  {
    bf16x8 k0r = *(const bf16x8*)(kt0 + (size_t)tid * 8);
    bf16x8 k1r = *(const bf16x8*)(kt0 + (size_t)(tid + 256) * 8);
    bf16x8 v0r = *(const bf16x8*)(vt0 + (size_t)tid * 8);
    bf16x8 v1r = *(const bf16x8*)(vt0 + (size_t)(tid + 256) * 8);
    *(bf16x8*)(&lds_k[tid * 8])         = k0r;
    *(bf16x8*)(&lds_k[(tid + 256) * 8]) = k1r;
    *(bf16x8*)(&lds_v[tid * 8])         = v0r;
    *(bf16x8*)(&lds_v[(tid + 256) * 8]) = v1r;
  }

  for (int kt = 0; kt < ntile; kt++) {
    const int k0 = kt * 64;

    __syncthreads();                         // staged tile kt visible

    // ---- QK batched: halves-of-4 ds_reads, then indep-accum MFMA pairs ----
    // S^T = K Q^T -> C[row = key-local quad*4+r][col = qrow-local l16]
    f32x4 acc[4];
#pragma unroll
    for (int h = 0; h < 2; h++) {
      bf16x8 kb[4];
#pragma unroll
      for (int nt2 = 0; nt2 < 2; nt2++)
#pragma unroll
        for (int kc = 0; kc < 2; kc++) {
          const int nt = h * 2 + nt2;
          kb[nt2 * 2 + kc] =
              *(const bf16x8*)(&lds_k[(((nt * 2 + kc) * 4 + quad) * 16 + l16) * 8]);
        }
#pragma unroll
      for (int nt2 = 0; nt2 < 2; nt2++) {
        const int nt = h * 2 + nt2;
        f32x4 A = (f32x4){0.f, 0.f, 0.f, 0.f};
        A = __builtin_amdgcn_mfma_f32_16x16x32_bf16(kb[nt2 * 2 + 0], qfrag[0], A, 0, 0, 0);
        A = __builtin_amdgcn_mfma_f32_16x16x32_bf16(kb[nt2 * 2 + 1], qfrag[1], A, 0, 0, 0);
        acc[nt] = A;
      }
    }

    // ---- softmax: one 16-exp batch; l_i stays per-lane partial (no shfl) ----
    const bool need_mask = (k0 + 63 > qw) || (k0 + 64 > len);
    float rs = 0.f;
    union { bf16x8 v[2]; uint32_t u[8]; } pa;  // PV A-frags, lane-local
#pragma unroll
    for (int nt = 0; nt < 4; nt++) {
      float e[4];
#pragma unroll
      for (int r = 0; r < 4; r++) {
        float x = fexp2(fmaf(acc[nt][r], C1_, -C2_));  // exp(s*scale-16); cancels at normalize
        if (need_mask) {
          const int key = k0 + nt * 16 + quad * 4 + r;
          x = (key <= km) ? x : 0.f;
        }
        e[r] = x; rs += x;
      }
      // zero-shuffle pack: pa[kc=nt>>1] elements j: nt&1 = j>>2, r = j&3
      const int ui = (nt >> 1) * 4 + (nt & 1) * 2;
      pa.u[ui]     = cvtpk(e[0], e[1]);
      pa.u[ui + 1] = cvtpk(e[2], e[3]);
    }
    l_i += rs;                               // cross-quad reduce deferred to epilogue

    // ---- PV batched in kc-halves (V k-order permuted in prep) ----
#pragma unroll
    for (int kc = 0; kc < 2; kc++) {
      bf16x8 vb[4];
#pragma unroll
      for (int nt = 0; nt < 4; nt++)
        vb[nt] = *(const bf16x8*)(&lds_v[(((nt * 2 + kc) * 4 + quad) * 16 + l16) * 8]);
#pragma unroll
      for (int nt = 0; nt < 4; nt++)
        ofrag[nt] = __builtin_amdgcn_mfma_f32_16x16x32_bf16(pa.v[kc], vb[nt], ofrag[nt], 0, 0, 0);
    }

    if (kt + 1 < ntile) {
      __syncthreads();                       // all waves done reading the buffer
      const unsigned short* kp = kt0 + (size_t)(kt + 1) * 4096;
      const unsigned short* vp = vt0 + (size_t)(kt + 1) * 4096;
      bf16x8 k0r = *(const bf16x8*)(kp + tid * 8);
      bf16x8 k1r = *(const bf16x8*)(kp + (tid + 256) * 8);
      bf16x8 v0r = *(const bf16x8*)(vp + tid * 8);
      bf16x8 v1r = *(const bf16x8*)(vp + (tid + 256) * 8);
      *(bf16x8*)(&lds_k[tid * 8])         = k0r;   // restage (latency covered by
      *(bf16x8*)(&lds_k[(tid + 256) * 8]) = k1r;   //  the CU's other 7 blocks)
      *(bf16x8*)(&lds_v[tid * 8])         = v0r;
      *(bf16x8*)(&lds_v[(tid + 256) * 8]) = v1r;
    }
  }

  // epilogue: cross-quad row-sum reduce (deferred from the loop), then store.
  l_i += __shfl_xor(l_i, 16);
  l_i += __shfl_xor(l_i, 32);                // all lanes: full sum for row l16
#pragma unroll
  for (int r = 0; r < 4; r++) {
    float l = __shfl(l_i, quad * 4 + r);     // lane s<16 holds row s's full sum
    float inv = (l > 0.f) ? 1.0f / l : 0.f;
    const int qrow2 = qw + quad * 4 + r;
    float* orow = outg + ((size_t)bh * S_ + qrow2) * D_;
#pragma unroll
    for (int nt = 0; nt < 4; nt++)
      orow[nt * 16 + l16] = ofrag[nt][r] * inv;
  }
}

extern "C" void kernel_launch(void* const* d_in, const int* in_sizes, int n_in,
                              void* d_out, int out_size, void* d_ws, size_t ws_size,
                              hipStream_t stream) {
  const float* q = (const float*)d_in[0];
  const float* k = (const float*)d_in[1];
  const float* v = (const float*)d_in[2];
  const void* posmask = d_in[3];
  const void* srcmask = d_in[4];
  float* out = (float*)d_out;

  unsigned short* kws  = (unsigned short*)d_ws;          // 2*BHSD*2 = 33.6 MB fits
  unsigned short* vtws = kws + (size_t)BHSD;

  hipLaunchKernelGGL(prep_kv_kernel, dim3(B_ * H_ * 16), dim3(256), 0, stream, k, v, kws, vtws);
  hipLaunchKernelGGL(attn_flash_kernel, dim3(B_ * H_ * 16), dim3(256), 0, stream,
                     q, kws, vtws, posmask, srcmask, out);
}

// Round 10
// 173.063 us; speedup vs baseline: 1.3127x; 1.3127x over previous
//
#include <hip/hip_runtime.h>
#include <stdint.h>

// B=8,H=16,S=1024,D=64 causal+length-masked attention. fp32 in/out.
// R16: R14 (53us champion) + async global_load_lds staging + setprio.
// R15 lesson: launch_bounds(256,8) caps unified VGPR+AGPR at 64 -> compiler
// carved 32 arch + spilled (WRITE 33->88MB); 8 waves/SIMD infeasible for
// this body. Residency ceiling is 16 waves/CU. So attack the issue stream
// instead: staging was 4 global_load_dwordx4 (16 VGPRs live across the
// whole compute) + 4 ds_write_b128 per thread per phase. Replace with 4
// __builtin_amdgcn_global_load_lds(...,16,..) DMAs: zero registers, zero
// ds_writes, loads stay in flight during compute. Our staging layout is
// exactly the required wave-uniform-base + lane*16B linear form
// (lds[tid*16B] <- g[base+tid*16B]). Correctness: compiler emits
// s_waitcnt vmcnt(0) before every s_barrier (m97-verified); explicit
// drain added anyway. T5: s_setprio(1) around QK/PV MFMA clusters
// (multi-block attn = phase diversity, +4-7% measured in learn_hip m191).
// Keeps: R14 batched body (kb[4]/vb[4] halves, 16-exp batch), deferred
// cross-quad rowsum, uniform chunk pairing {c,15-c}, zero-shuffle PV
// (V key-permuted in prep), cvt_pk, XCD swizzle (16 bh = 4MB per XCD L2),
// double-buffered LDS, grid 1024 = 4 blocks/CU.
// Spill tripwire: WRITE_SIZE must stay ~33MB.
#define B_ 8
#define H_ 16
#define S_ 1024
#define D_ 64
#define C1_ 0.18033688f          // 0.125 * log2(e)
#define C2_ 23.08312065f         // 16 * log2(e)
#define BHSD (B_ * H_ * S_ * D_)

typedef __attribute__((ext_vector_type(8))) short bf16x8;
typedef __attribute__((ext_vector_type(4))) float f32x4;
typedef __attribute__((ext_vector_type(4))) unsigned short us4;

__device__ __forceinline__ unsigned short f2bf(float f) {
  union { float f; uint32_t u; } v; v.f = f;
  return (unsigned short)((v.u + 0x7fffu + ((v.u >> 16) & 1u)) >> 16);  // RNE
}
__device__ __forceinline__ uint32_t cvtpk(float lo, float hi) {  // HW RNE pack
  uint32_t r;
  asm("v_cvt_pk_bf16_f32 %0, %1, %2" : "=v"(r) : "v"(lo), "v"(hi));
  return r;
}
__device__ __forceinline__ float fexp2(float x) {
#if __has_builtin(__builtin_amdgcn_exp2f)
  return __builtin_amdgcn_exp2f(x);
#else
  return exp2f(x);
#endif
}
// async 16B global->LDS DMA; dest = wave-uniform base + lane*16 (linear)
__device__ __forceinline__ void gl16(const unsigned short* g, unsigned short* l) {
  __builtin_amdgcn_global_load_lds(
      (const __attribute__((address_space(1))) unsigned int*)g,
      (__attribute__((address_space(3))) unsigned int*)l, 16, 0, 0);
}

// Chunk-major tile layout (per bh, per 64-key tile kt; 512 chunks of 8 bf16):
//   chunk c = ((nt*2+kc)*4+quad)*16 + l16
//   K  chunk holds K [key = kt*64 + nt*16 + l16][d = kc*32 + quad*8 + j]
//   Vt chunk holds Vt[d   = nt*16 + l16       ]
//                    [key = kt*64 + kc*32 + (j>>2)*16 + quad*4 + (j&3)]
// (V's j-mapping matches the QK C-layout so PV needs NO P redistribution.)
__global__ __launch_bounds__(256) void prep_kv_kernel(
    const float* __restrict__ kg, const float* __restrict__ vg,
    unsigned short* __restrict__ kws, unsigned short* __restrict__ vtws) {
  __shared__ unsigned short t[64 * 68];
  const int tid = threadIdx.x;
  const int kt  = blockIdx.x & 15;
  const int bh  = blockIdx.x >> 4;
  const size_t off  = ((size_t)bh * S_ + kt * 64) * D_;
  const size_t tout = (size_t)(bh * 16 + kt) * 4096;
  // K: coalesced float4 load -> LDS [key][d] -> d-contiguous chunk gather
#pragma unroll
  for (int i = 0; i < 4; i++) {
    int c = tid + 256 * i;                 // 1024 float4 = 64x64 fp32 tile
    float4 val = *(const float4*)(kg + off + c * 4);
    int key = c >> 4, d0 = (c & 15) * 4;
    us4 o; o[0] = f2bf(val.x); o[1] = f2bf(val.y); o[2] = f2bf(val.z); o[3] = f2bf(val.w);
    *(us4*)(&t[key * 68 + d0]) = o;
  }
  __syncthreads();
#pragma unroll
  for (int i = 0; i < 2; i++) {
    int c = tid + 256 * i;
    int nt = c >> 7, kc = (c >> 6) & 1, quad = (c >> 4) & 3, l16 = c & 15;
    int key = nt * 16 + l16, d0 = kc * 32 + quad * 8;
    bf16x8 o;
#pragma unroll
    for (int j = 0; j < 8; j++) o[j] = (short)t[key * 68 + d0 + j];
    *(bf16x8*)(kws + tout + (size_t)c * 8) = o;
  }
  __syncthreads();                         // t reused for V
  // V: coalesced load -> LDS -> transposed chunk-major gather (permuted keys)
#pragma unroll
  for (int i = 0; i < 4; i++) {
    int c = tid + 256 * i;
    float4 val = *(const float4*)(vg + off + c * 4);
    int key = c >> 4, d0 = (c & 15) * 4;
    us4 o; o[0] = f2bf(val.x); o[1] = f2bf(val.y); o[2] = f2bf(val.z); o[3] = f2bf(val.w);
    *(us4*)(&t[key * 68 + d0]) = o;
  }
  __syncthreads();
#pragma unroll
  for (int i = 0; i < 2; i++) {
    int c = tid + 256 * i;
    int nt = c >> 7, kc = (c >> 6) & 1, quad = (c >> 4) & 3, l16 = c & 15;
    int d = nt * 16 + l16, kb2 = kc * 32 + quad * 4;
    bf16x8 o;
#pragma unroll
    for (int j = 0; j < 8; j++) {
      int key = kb2 + ((j >> 2) << 4) + (j & 3);
      o[j] = (short)t[key * 68 + d];
    }
    *(bf16x8*)(vtws + tout + (size_t)c * 8) = o;
  }
}

// ---- flash attention: 256 thr = 4 waves x 16 q-rows; chunk pair {c,15-c} ----
__global__ __launch_bounds__(256, 4) void attn_flash_kernel(
    const float* __restrict__ qg,
    const unsigned short* __restrict__ kws,   // chunk-major bf16 K tiles
    const unsigned short* __restrict__ vtws,  // chunk-major bf16 Vt tiles
    const void* __restrict__ posmask,
    const void* __restrict__ srcmask,
    float* __restrict__ outg)
{
  __shared__ unsigned short lds_k[2][4096];
  __shared__ unsigned short lds_v[2][4096];

  const int tid  = threadIdx.x;
  const int wave = tid >> 6;                 // 0..3
  const int lane = tid & 63;
  const int quad = lane >> 4;
  const int l16  = lane & 15;

  // Block p -> XCD p&7, i = p>>3 in [0,128): bh = xcd*16 + (i>>3)
  // (16 bh per XCD -> 4MB K/V resident in its L2); pair index c = i&7.
  // Block processes 64-row chunks c then 15-c: uniform ~17 tiles/block.
  const int p   = blockIdx.x;
  const int xcd = p & 7;
  const int i   = p >> 3;
  const int bh  = xcd * 16 + (i >> 3);
  const int c   = i & 7;
  const int b   = bh >> 4;

  // mask element-width probe from position_mask (elem0=0, elem1=1)
  const uint8_t* pmb = (const uint8_t*)posmask;
  const int mode = pmb[1] ? 0 : (pmb[2] ? 1 : (pmb[4] ? 2 : 3));

  // wave-local source-length reduction (no LDS, no barrier, no atomic)
  int lm = S_;
  for (int ii = lane; ii < S_; ii += 64) {
    const int idx = b * S_ + ii;
    bool masked;
    if (mode == 0)      masked = ((const uint8_t*) srcmask)[idx] != 0;
    else if (mode == 1) masked = ((const uint16_t*)srcmask)[idx] != 0;
    else                masked = ((const uint32_t*)srcmask)[idx] != 0;
    if (masked) lm = min(lm, ii);
  }
  lm = min(lm, __shfl_xor(lm, 1));
  lm = min(lm, __shfl_xor(lm, 2));
  lm = min(lm, __shfl_xor(lm, 4));
  lm = min(lm, __shfl_xor(lm, 8));
  lm = min(lm, __shfl_xor(lm, 16));
  lm = min(lm, __shfl_xor(lm, 32));
  const int len = lm;

  const unsigned short* kt0 = kws  + (size_t)bh * 16 * 4096;
  const unsigned short* vt0 = vtws + (size_t)bh * 16 * 4096;

#pragma unroll
  for (int item = 0; item < 2; item++) {
    const int qb = item ? (15 - c) : c;      // 64-row chunk index 0..15
    const int qw = qb * 64 + wave * 16;      // this wave's 16 q rows

    // prior item's LDS reads done -> issue tile-0 DMA first (critical path),
    // then Q-frag loads overlap the DMA.
    __syncthreads();
    gl16(kt0 + (size_t)tid * 8,         &lds_k[0][tid * 8]);
    gl16(kt0 + (size_t)(tid + 256) * 8, &lds_k[0][(tid + 256) * 8]);
    gl16(vt0 + (size_t)tid * 8,         &lds_v[0][tid * 8]);
    gl16(vt0 + (size_t)(tid + 256) * 8, &lds_v[0][(tid + 256) * 8]);

    // Q B-frags (S^T form): lane l16 = qrow-local, quad*8+j = d
    bf16x8 qfrag[2];
#pragma unroll
    for (int kc = 0; kc < 2; kc++) {
      const float* qp = qg + ((size_t)bh * S_ + qw + l16) * D_ + kc * 32 + quad * 8;
      float4 a = *(const float4*)qp;
      float4 cc = *(const float4*)(qp + 4);
      union { bf16x8 v; uint32_t u[4]; } u;
      u.u[0] = cvtpk(a.x, a.y);  u.u[1] = cvtpk(a.z, a.w);
      u.u[2] = cvtpk(cc.x, cc.y); u.u[3] = cvtpk(cc.z, cc.w);
      qfrag[kc] = u.v;
    }

    f32x4 ofrag[4];
#pragma unroll
    for (int nt = 0; nt < 4; nt++) ofrag[nt] = (f32x4){0.f, 0.f, 0.f, 0.f};
    float l_i = 0.f;                         // per-lane PARTIAL (own quad's keys)

    const int kend  = min(qb * 64 + 64, len);
    const int ntile = (kend + 63) >> 6;      // block-uniform (qb,len uniform)
    const int km    = min(qw + l16, len - 1);

    for (int kt = 0; kt < ntile; kt++) {
      const int k0  = kt * 64;
      const int buf = kt & 1;
      const bool more = (kt + 1 < ntile);

      // drain own DMA (prologue or prev phase), then rendezvous:
      // all waves' chunks of buf are complete and visible.
      asm volatile("s_waitcnt vmcnt(0)" ::: "memory");
      __syncthreads();

      if (more) {                            // issue next tile's DMA into buf^1
        const unsigned short* kp = kt0 + (size_t)(kt + 1) * 4096;
        const unsigned short* vp = vt0 + (size_t)(kt + 1) * 4096;
        unsigned short* dk = &lds_k[buf ^ 1][0];
        unsigned short* dv = &lds_v[buf ^ 1][0];
        gl16(kp + (size_t)tid * 8,         dk + tid * 8);
        gl16(kp + (size_t)(tid + 256) * 8, dk + (tid + 256) * 8);
        gl16(vp + (size_t)tid * 8,         dv + tid * 8);
        gl16(vp + (size_t)(tid + 256) * 8, dv + (tid + 256) * 8);
      }

      // ---- QK batched: halves-of-4 ds_reads, then indep-accum MFMA pairs ----
      // S^T = K Q^T -> C[row = key-local quad*4+r][col = qrow-local l16]
      f32x4 acc[4];
#pragma unroll
      for (int h = 0; h < 2; h++) {
        bf16x8 kb[4];
#pragma unroll
        for (int nt2 = 0; nt2 < 2; nt2++)
#pragma unroll
          for (int kc = 0; kc < 2; kc++) {
            const int nt = h * 2 + nt2;
            kb[nt2 * 2 + kc] =
                *(const bf16x8*)(&lds_k[buf][(((nt * 2 + kc) * 4 + quad) * 16 + l16) * 8]);
          }
        __builtin_amdgcn_s_setprio(1);
#pragma unroll
        for (int nt2 = 0; nt2 < 2; nt2++) {
          const int nt = h * 2 + nt2;
          f32x4 A = (f32x4){0.f, 0.f, 0.f, 0.f};
          A = __builtin_amdgcn_mfma_f32_16x16x32_bf16(kb[nt2 * 2 + 0], qfrag[0], A, 0, 0, 0);
          A = __builtin_amdgcn_mfma_f32_16x16x32_bf16(kb[nt2 * 2 + 1], qfrag[1], A, 0, 0, 0);
          acc[nt] = A;
        }
        __builtin_amdgcn_s_setprio(0);
      }

      // ---- softmax: one 16-exp batch; l_i stays per-lane partial (no shfl) ----
      const bool need_mask = (k0 + 63 > qw) || (k0 + 64 > len);
      float rs = 0.f;
      union { bf16x8 v[2]; uint32_t u[8]; } pa;  // PV A-frags, lane-local
#pragma unroll
      for (int nt = 0; nt < 4; nt++) {
        float e[4];
#pragma unroll
        for (int r = 0; r < 4; r++) {
          float x = fexp2(fmaf(acc[nt][r], C1_, -C2_));  // exp(s*scale-16); cancels at normalize
          if (need_mask) {
            const int key = k0 + nt * 16 + quad * 4 + r;
            x = (key <= km) ? x : 0.f;
          }
          e[r] = x; rs += x;
        }
        // zero-shuffle pack: pa[kc=nt>>1] elements j: nt&1 = j>>2, r = j&3
        const int ui = (nt >> 1) * 4 + (nt & 1) * 2;
        pa.u[ui]     = cvtpk(e[0], e[1]);
        pa.u[ui + 1] = cvtpk(e[2], e[3]);
      }
      l_i += rs;                             // cross-quad reduce deferred to epilogue

      // ---- PV batched in kc-halves (V k-order permuted in prep) ----
#pragma unroll
      for (int kc = 0; kc < 2; kc++) {
        bf16x8 vb[4];
#pragma unroll
        for (int nt = 0; nt < 4; nt++)
          vb[nt] = *(const bf16x8*)(&lds_v[buf][(((nt * 2 + kc) * 4 + quad) * 16 + l16) * 8]);
        __builtin_amdgcn_s_setprio(1);
#pragma unroll
        for (int nt = 0; nt < 4; nt++)
          ofrag[nt] = __builtin_amdgcn_mfma_f32_16x16x32_bf16(pa.v[kc], vb[nt], ofrag[nt], 0, 0, 0);
        __builtin_amdgcn_s_setprio(0);
      }
    }

    // epilogue: cross-quad row-sum reduce (deferred from the loop), then store.
    l_i += __shfl_xor(l_i, 16);
    l_i += __shfl_xor(l_i, 32);              // all lanes: full sum for row l16
#pragma unroll
    for (int r = 0; r < 4; r++) {
      float l = __shfl(l_i, quad * 4 + r);   // lane s<16 holds row s's full sum
      float inv = (l > 0.f) ? 1.0f / l : 0.f;
      const int qrow2 = qw + quad * 4 + r;
      float* orow = outg + ((size_t)bh * S_ + qrow2) * D_;
#pragma unroll
      for (int nt = 0; nt < 4; nt++)
        orow[nt * 16 + l16] = ofrag[nt][r] * inv;
    }
  }
}

extern "C" void kernel_launch(void* const* d_in, const int* in_sizes, int n_in,
                              void* d_out, int out_size, void* d_ws, size_t ws_size,
                              hipStream_t stream) {
  const float* q = (const float*)d_in[0];
  const float* k = (const float*)d_in[1];
  const float* v = (const float*)d_in[2];
  const void* posmask = d_in[3];
  const void* srcmask = d_in[4];
  float* out = (float*)d_out;

  unsigned short* kws  = (unsigned short*)d_ws;          // 2*BHSD*2 = 33.6 MB fits
  unsigned short* vtws = kws + (size_t)BHSD;

  hipLaunchKernelGGL(prep_kv_kernel, dim3(B_ * H_ * 16), dim3(256), 0, stream, k, v, kws, vtws);
  hipLaunchKernelGGL(attn_flash_kernel, dim3(B_ * H_ * 8), dim3(256), 0, stream,
                     q, kws, vtws, posmask, srcmask, out);
}